// Round 11
// baseline (61.958 us; speedup 1.0000x reference)
//
#include <hip/hip_runtime.h>
#include <stdint.h>

// Problem constants
#define D_DIM 512
#define B_ROWS 4096
#define N_ROWS 8192
// (1/TEMPERATURE) * log2(e) : exp(x/T) == exp2(x * SCALE_L2E)
#define SCALE_L2E 14.426950408889634f

#define NHP 8                       // K-blocks of 64 (each = two K=32 MFMA steps)
#define BM 128                      // pair-tile edge
#define NT (N_ROWS / BM)            // 64 tiles of 128 rows
// Supers of 8 tiles (1024 rows): 8 supers. Super-pairs (SI<=SJ): 36.
// Sub-pairs: diag super = 36, off-diag = 64. Total = 8*36 + 28*64 = 2080 = 8*260.
#define NBLK 2080

typedef __attribute__((ext_vector_type(4))) float f32x4;
typedef __attribute__((ext_vector_type(2))) long f8x16;  // 16 fp8 bytes = dwordx4

// ---------------- K1: normalize rows -> fp8 e4m3 Zn (hp-interleaved), fp32 pos -------------
// Zn layout: [hp=0..7][row=0..8191][64 B]; byte slot lhi*16 holds k-octet (64hp+lhi*8..+8)
// and slot lhi*16+8 holds (64hp+32+lhi*8..+8) => one dwordx4 fragment load provides the
// MFMA A/B operands for BOTH K=32 steps of the hp.
__global__ __launch_bounds__(256) void k_normalize(const float* __restrict__ zi,
                                                   const float* __restrict__ zj,
                                                   unsigned char* __restrict__ Zn,
                                                   float* __restrict__ pos) {
    const int t = threadIdx.x;
    const int lane = t & 63;
    const int i = blockIdx.x * 4 + (t >> 6);
    const float* pa = zi + (size_t)i * D_DIM + lane * 8;
    const float* pb = zj + (size_t)i * D_DIM + lane * 8;
    const float4 a0 = *(const float4*)pa;
    const float4 a1 = *(const float4*)(pa + 4);
    const float4 b0 = *(const float4*)pb;
    const float4 b1 = *(const float4*)(pb + 4);
    float ssi = a0.x*a0.x + a0.y*a0.y + a0.z*a0.z + a0.w*a0.w
              + a1.x*a1.x + a1.y*a1.y + a1.z*a1.z + a1.w*a1.w;
    float ssj = b0.x*b0.x + b0.y*b0.y + b0.z*b0.z + b0.w*b0.w
              + b1.x*b1.x + b1.y*b1.y + b1.z*b1.z + b1.w*b1.w;
    float dt  = a0.x*b0.x + a0.y*b0.y + a0.z*b0.z + a0.w*b0.w
              + a1.x*b1.x + a1.y*b1.y + a1.z*b1.z + a1.w*b1.w;
    #pragma unroll
    for (int off = 1; off < 64; off <<= 1) {
        ssi += __shfl_xor(ssi, off);
        ssj += __shfl_xor(ssj, off);
        dt  += __shfl_xor(dt,  off);
    }
    const float si = 1.0f / fmaxf(sqrtf(ssi), 1e-12f);
    const float sj = 1.0f / fmaxf(sqrtf(ssj), 1e-12f);
    // pack 8 normalized values (k = lane*8 .. +8) -> 8 fp8 e4m3 (HW RNE)
    uint2 pi8, pj8;
    {
        int w0 = 0, w1 = 0;
        w0 = __builtin_amdgcn_cvt_pk_fp8_f32(a0.x * si, a0.y * si, w0, false);
        w0 = __builtin_amdgcn_cvt_pk_fp8_f32(a0.z * si, a0.w * si, w0, true);
        w1 = __builtin_amdgcn_cvt_pk_fp8_f32(a1.x * si, a1.y * si, w1, false);
        w1 = __builtin_amdgcn_cvt_pk_fp8_f32(a1.z * si, a1.w * si, w1, true);
        pi8.x = (unsigned)w0; pi8.y = (unsigned)w1;
        w0 = 0; w1 = 0;
        w0 = __builtin_amdgcn_cvt_pk_fp8_f32(b0.x * sj, b0.y * sj, w0, false);
        w0 = __builtin_amdgcn_cvt_pk_fp8_f32(b0.z * sj, b0.w * sj, w0, true);
        w1 = __builtin_amdgcn_cvt_pk_fp8_f32(b1.x * sj, b1.y * sj, w1, false);
        w1 = __builtin_amdgcn_cvt_pk_fp8_f32(b1.z * sj, b1.w * sj, w1, true);
        pj8.x = (unsigned)w0; pj8.y = (unsigned)w1;
    }
    // lane's k-octet o = lane&7 within hp = lane>>3; byte slot = (o&3)*16 + (o>>2)*8
    const size_t PLANE = (size_t)N_ROWS * 64;  // bytes per hp-plane
    const int o = lane & 7;
    const size_t off0 = (size_t)(lane >> 3) * PLANE + (o & 3) * 16 + (o >> 2) * 8;
    *(uint2*)(Zn + off0 + (size_t)i * 64) = pi8;
    *(uint2*)(Zn + off0 + (size_t)(B_ROWS + i) * 64) = pj8;
    if (lane == 0) pos[i] = 20.0f * dt * si * sj;  // positive logit counted twice: 2*dot/T
}

// ---------------- K2: symmetric fused S = Zn·Zn^T (fp8 MFMA) + per-row sum(exp(S/T)) ------
// 128x128 tile pair (I<=J) per block; 256 threads = 4 waves (2x2), each wave one 64x64
// quadrant. NO LDS / barriers; fragments load directly global->VGPR. The 2x2 wave grid
// makes every A-slice requested by 2 waves and every B-slice by 2 waves concurrently ->
// L1/MSHR merging halves L2 requests. Supertiled enumeration (supers of 8 tiles) keeps the
// per-super-pair working set at 1 MiB (L2-resident). 4 waves/SIMD (VGPR<=128).
__global__ __launch_bounds__(256, 4) void k_gemm_lse(const unsigned char* __restrict__ Zn,
                                                     float* __restrict__ rowsum_g) {
    const int t    = threadIdx.x;
    const int lane = t & 63;
    const int w    = t >> 6;
    const int wm   = w >> 1, wn = w & 1;          // 2 x 2 wave grid
    const int l15  = lane & 15, lhi = lane >> 4;

    // XCD-aware swizzle (bijective: NBLK % 8 == 0)
    int g = (blockIdx.x & 7) * (NBLK / 8) + (blockIdx.x >> 3);
    // super-pair decode (SI<=SJ over 8 supers; sizes 36 diag / 64 off-diag)
    int SI = 0, SJ = 0;
    {
        bool found = false;
        for (SI = 0; SI < 8 && !found; ++SI) {
            for (SJ = SI; SJ < 8; ++SJ) {
                const int sz = (SI == SJ) ? 36 : 64;
                if (g < sz) { found = true; break; }
                g -= sz;
            }
        }
        --SI;  // loop increments past the found value
    }
    int di, dj;
    if (SI == SJ) {
        di = 0;
        while (g >= 8 - di) { g -= 8 - di; ++di; }
        dj = di + g;
    } else {
        di = g >> 3; dj = g & 7;
    }
    const int I = SI * 8 + di, J = SJ * 8 + dj;
    const bool dg = (I == J);
    const int rowB = I * BM + wm * 64;     // wave's first output row
    const int colB = J * BM + wn * 64;     // wave's first output col

    const char* Zb = (const char*)Zn;
    const size_t PLANE = (size_t)N_ROWS * 64;  // bytes per hp-plane

    // fragment base pointers: lane (lhi,l15) reads row (base + l15 + 16*frag), slot lhi
    const char* pA = Zb + ((size_t)(rowB + l15)) * 64 + lhi * 16;
    const char* pB = Zb + ((size_t)(colB + l15)) * 64 + lhi * 16;

    f32x4 acc[4][4];
    #pragma unroll
    for (int a = 0; a < 4; ++a)
        #pragma unroll
        for (int b = 0; b < 4; ++b)
            #pragma unroll
            for (int q = 0; q < 4; ++q) acc[a][b][q] = 0.0f;

    for (int hp = 0; hp < NHP; ++hp) {
        f8x16 af[4], bg[4];
        const char* _a = pA + (size_t)hp * PLANE;
        const char* _b = pB + (size_t)hp * PLANE;
        #pragma unroll
        for (int mi = 0; mi < 4; ++mi) af[mi] = *(const f8x16*)(_a + mi * 1024);
        #pragma unroll
        for (int ni = 0; ni < 4; ++ni) bg[ni] = *(const f8x16*)(_b + ni * 1024);
        __builtin_amdgcn_s_setprio(1);
        #pragma unroll
        for (int mi = 0; mi < 4; ++mi)
            #pragma unroll
            for (int ni = 0; ni < 4; ++ni)
                acc[mi][ni] = __builtin_amdgcn_mfma_f32_16x16x32_fp8_fp8(
                    af[mi][0], bg[ni][0], acc[mi][ni], 0, 0, 0);
        #pragma unroll
        for (int mi = 0; mi < 4; ++mi)
            #pragma unroll
            for (int ni = 0; ni < 4; ++ni)
                acc[mi][ni] = __builtin_amdgcn_mfma_f32_16x16x32_fp8_fp8(
                    af[mi][1], bg[ni][1], acc[mi][ni], 0, 0, 0);
        __builtin_amdgcn_s_setprio(0);
    }

    // epilogue: e = exp2(S * 10*log2e); C/D layout: col=lane&15, row=(lane>>4)*4+reg
    float colsum[4] = {0.0f, 0.0f, 0.0f, 0.0f};
    #pragma unroll
    for (int mi = 0; mi < 4; ++mi) {
        const int growb = rowB + mi * 16 + lhi * 4;
        float rs[4] = {0.0f, 0.0f, 0.0f, 0.0f};
        if (dg && wm == wn) {
            #pragma unroll
            for (int ni = 0; ni < 4; ++ni) {
                const int gcol = colB + ni * 16 + l15;
                #pragma unroll
                for (int r = 0; r < 4; ++r) {
                    float arg = acc[mi][ni][r] * SCALE_L2E;
                    if (growb + r == gcol) arg = -1e30f;  // diagonal mask -> exp2 = 0
                    rs[r] += exp2f(arg);
                }
            }
        } else {
            #pragma unroll
            for (int ni = 0; ni < 4; ++ni)
                #pragma unroll
                for (int r = 0; r < 4; ++r) {
                    const float e = exp2f(acc[mi][ni][r] * SCALE_L2E);
                    rs[r] += e;
                    colsum[ni] += e;
                }
        }
        // row sums: reduce the 16 lanes sharing lhi; one atomic per (mi, r)
        #pragma unroll
        for (int r = 0; r < 4; ++r) {
            float v = rs[r];
            v += __shfl_xor(v, 1);
            v += __shfl_xor(v, 2);
            v += __shfl_xor(v, 4);
            v += __shfl_xor(v, 8);
            if (l15 == 0) atomicAdd(&rowsum_g[growb + r], v);
        }
    }
    // column sums (symmetry) for every quadrant strictly above the global diagonal.
    // Diagonal pair blocks (dg): quadrants (0,1)/(1,0) compute the same values; only
    // (wm<wn) contributes col sums (the (1,0) quadrant's transpose IS (0,1)'s output).
    if (!dg ? true : (wm < wn)) {
        if (!(dg && wm == wn)) {
            #pragma unroll
            for (int ni = 0; ni < 4; ++ni) {
                float c = colsum[ni];
                c += __shfl_xor(c, 16);
                c += __shfl_xor(c, 32);
                if (lhi == 0)
                    atomicAdd(&rowsum_g[colB + ni * 16 + l15], c);
            }
        }
    }
    // NOTE: for dg blocks the (1,0) quadrant (wm>wn) computed S for rows 64-127 x cols 0-63,
    // which duplicates (0,1)^T. Its ROW sums are needed (rows 64-127 get their cols 0-63
    // contribution) -- handled above -- but its col sums would double-count rows 64-127
    // contributions already covered by (0,1)'s row sums, hence the wm<wn guard.
}

// ---------------- K3: loss = mean(ln(rowsum)) - mean(pos), single block ----------------
__global__ __launch_bounds__(1024) void k_finalize(const float* __restrict__ rowsum_g,
                                                   const float* __restrict__ pos,
                                                   float* __restrict__ out) {
    const int t = threadIdx.x;
    float l = 0.0f, p = 0.0f;
    #pragma unroll
    for (int q = 0; q < N_ROWS / 1024; ++q) l += logf(rowsum_g[t + q * 1024]);
    #pragma unroll
    for (int q = 0; q < B_ROWS / 1024; ++q) p += pos[t + q * 1024];
    #pragma unroll
    for (int off = 1; off < 64; off <<= 1) {
        l += __shfl_xor(l, off);
        p += __shfl_xor(p, off);
    }
    __shared__ float red[2][16];
    if ((t & 63) == 0) { red[0][t >> 6] = l; red[1][t >> 6] = p; }
    __syncthreads();
    if (t == 0) {
        float L = 0.0f, P = 0.0f;
        #pragma unroll
        for (int q = 0; q < 16; ++q) { L += red[0][q]; P += red[1][q]; }
        out[0] = (L - P) * (1.0f / (float)N_ROWS);
    }
}

extern "C" void kernel_launch(void* const* d_in, const int* in_sizes, int n_in,
                              void* d_out, int out_size, void* d_ws, size_t ws_size,
                              hipStream_t stream) {
    (void)in_sizes; (void)n_in; (void)out_size; (void)ws_size;
    const float* zi = (const float*)d_in[0];
    const float* zj = (const float*)d_in[1];

    // workspace layout
    const size_t ZN_BYTES = (size_t)N_ROWS * D_DIM;  // 4 MiB fp8 (hp-tiled)
    unsigned char* Zn     = (unsigned char*)d_ws;
    float* rowsum_g       = (float*)((char*)d_ws + ZN_BYTES);              // 8192 f32
    float* pos            = (float*)((char*)d_ws + ZN_BYTES + N_ROWS * 4); // 4096 f32

    // zero the atomically-accumulated rowsums
    hipMemsetAsync(rowsum_g, 0, N_ROWS * 4, stream);

    k_normalize<<<B_ROWS / 4, 256, 0, stream>>>(zi, zj, Zn, pos);
    k_gemm_lse<<<NBLK, 256, 0, stream>>>(Zn, rowsum_g);
    k_finalize<<<1, 1024, 0, stream>>>(rowsum_g, pos, (float*)d_out);
}